// Round 2
// baseline (121.858 us; speedup 1.0000x reference)
//
#include <hip/hip_runtime.h>

#define NT 256
#define RCHUNK 32
#define NSLOT 32

// ws accumulator layout: [level*2 + stat][slot], stat 0 = l2, 1 = cc. 256 floats.

__device__ __forceinline__ void wave_fence_after_write() {
    // staging ds_writes must be visible to cross-lane ds_reads that follow
    __builtin_amdgcn_wave_barrier();
    asm volatile("s_waitcnt lgkmcnt(0)" ::: "memory");
    __builtin_amdgcn_sched_barrier(0);
}
__device__ __forceinline__ void wave_fence_after_read() {
    // keep this iteration's ds_reads before next iteration's ds_writes
    __builtin_amdgcn_wave_barrier();
    __builtin_amdgcn_sched_barrier(0);
}

template<int W, int H, int WIN, int SCALE>
__device__ void level_wave(const float* __restrict__ yh,
                           const float* __restrict__ y,
                           int sub, float* __restrict__ ws_acc, int level,
                           float* rawI, float* rawJ)
{
    constexpr int HW = WIN / 2;
    constexpr int RW = 64 + 2 * HW;
    constexpr int T  = RCHUNK + 2 * HW;
    constexpr int G  = (T + WIN - 1) / WIN;
    constexpr float INV_WS = 1.0f / (float)(WIN * WIN);

    constexpr int STRIPS = W / 64;
    constexpr int CHUNKS = H / RCHUNK;
    int b     = sub / (STRIPS * CHUNKS);
    int rem   = sub % (STRIPS * CHUNKS);
    int chunk = rem / STRIPS;
    int strip = rem % STRIPS;
    int r0 = chunk * RCHUNK;
    int c0 = strip * 64;

    const float* Jimg = yh + (size_t)b * W * H;
    const float* Yimg = y  + (size_t)b * 512 * 512;

    int l = threadIdx.x & 63;

    float ringI[WIN], ringJ[WIN], ringII[WIN], ringJJ[WIN], ringIJ[WIN];
#pragma unroll
    for (int k = 0; k < WIN; ++k) {
        ringI[k] = 0.f; ringJ[k] = 0.f; ringII[k] = 0.f; ringJJ[k] = 0.f; ringIJ[k] = 0.f;
    }
    float vI = 0.f, vJ = 0.f, vII = 0.f, vJJ = 0.f, vIJ = 0.f;
    float l2acc = 0.f, ccacc = 0.f;

    for (int g = 0; g < G; ++g) {
#pragma unroll
        for (int u = 0; u < WIN; ++u) {
            int rr = g * WIN + u;          // row index within the padded sweep
            int r  = r0 - HW + rr;         // image row
            bool rin = (rr < T) && (r >= 0) && (r < H);

            // ---- stage raw row (with column halo) into per-wave LDS ----
            {
                int j = c0 - HW + l;
                float I = 0.f, J = 0.f;
                if (rin && j >= 0 && j < W) {
                    J = Jimg[(size_t)r * W + j];
                    if (SCALE == 1) {
                        I = Yimg[(size_t)r * 512 + j];
                    } else {
                        constexpr int OFF = (SCALE - 2) / 2;
                        const float* p = Yimg + (size_t)(SCALE * r + OFF) * 512 + (SCALE * j + OFF);
                        I = 0.25f * (p[0] + p[1] + p[512] + p[513]);
                    }
                }
                rawI[l] = I;
                rawJ[l] = J;
                if (l < RW - 64) {
                    int j2 = j + 64;
                    float I2 = 0.f, J2 = 0.f;
                    if (rin && j2 < W) {
                        J2 = Jimg[(size_t)r * W + j2];
                        if (SCALE == 1) {
                            I2 = Yimg[(size_t)r * 512 + j2];
                        } else {
                            constexpr int OFF = (SCALE - 2) / 2;
                            const float* p = Yimg + (size_t)(SCALE * r + OFF) * 512 + (SCALE * j2 + OFF);
                            I2 = 0.25f * (p[0] + p[1] + p[512] + p[513]);
                        }
                    }
                    rawI[l + 64] = I2;
                    rawJ[l + 64] = J2;
                }
            }
            wave_fence_after_write();

            // ---- horizontal WIN-tap sums for this lane's column ----
            float sI = 0.f, sJ = 0.f, sII = 0.f, sJJ = 0.f, sIJ = 0.f;
            float Ic = 0.f, Jc = 0.f;
#pragma unroll
            for (int k = 0; k < WIN; ++k) {
                float I = rawI[l + k];
                float J = rawJ[l + k];
                if (k == HW) { Ic = I; Jc = J; }
                sI += I; sJ += J;
                sII = fmaf(I, I, sII);
                sJJ = fmaf(J, J, sJJ);
                sIJ = fmaf(I, J, sIJ);
            }
            wave_fence_after_read();

            // ---- l2 for own pixel (rows of this chunk only, counted once) ----
            if (rr >= HW && rr < RCHUNK + HW) {
                float d = Jc - Ic;
                l2acc = fmaf(d, d, l2acc);
            }

            // ---- push into register ring (slot = u, compile-time) ----
            ringI[u] = sI; ringJ[u] = sJ; ringII[u] = sII; ringJJ[u] = sJJ; ringIJ[u] = sIJ;
            vI += sI; vJ += sJ; vII += sII; vJJ += sJJ; vIJ += sIJ;

            // ---- emit output row (window full) and slide ----
            if (rr >= 2 * HW && rr < T) {
                float cross = fmaf(-(vI * vJ), INV_WS, vIJ);
                float Iv    = fmaf(-(vI * vI), INV_WS, vII);
                float Jv    = fmaf(-(vJ * vJ), INV_WS, vJJ);
                float cc = (cross * cross) / (Iv * Jv + 1e-8f);
                ccacc += cc;
                constexpr int dummy = 0; (void)dummy;
                const int us = (u + 1) % WIN;   // compile-time after unroll
                vI  -= ringI[us];
                vJ  -= ringJ[us];
                vII -= ringII[us];
                vJJ -= ringJJ[us];
                vIJ -= ringIJ[us];
            }
        }
    }

    // ---- wave reduction + atomics into slotted accumulators ----
#pragma unroll
    for (int off = 32; off > 0; off >>= 1) {
        l2acc += __shfl_down(l2acc, off);
        ccacc += __shfl_down(ccacc, off);
    }
    if (l == 0) {
        int slot = sub & (NSLOT - 1);
        atomicAdd(&ws_acc[(level * 2 + 0) * NSLOT + slot], l2acc);
        atomicAdd(&ws_acc[(level * 2 + 1) * NSLOT + slot], ccacc);
    }
}

__global__ __launch_bounds__(NT)
void hier_loss_kernel(const float* __restrict__ yh0, const float* __restrict__ yh1,
                      const float* __restrict__ yh2, const float* __restrict__ yh3,
                      const float* __restrict__ y, float* ws_acc)
{
    __shared__ float smem[4][2][80];
    int wave = threadIdx.x >> 6;
    float* rawI = &smem[wave][0][0];
    float* rawJ = &smem[wave][1][0];

    int wid = blockIdx.x * (NT / 64) + wave;
    // L0: 512x512: 8 strips x 16 chunks x 32 imgs = 4096 waves
    // L1: 256x256: 4 strips x  8 chunks x 32      = 1024 -> [4096,5120)
    // L2: 128x128: 2 strips x  4 chunks x 32      =  256 -> [5120,5376)
    // L3:  64x64 : 1 strip  x  2 chunks x 32      =   64 -> [5376,5440)
    if (wid < 4096) {
        level_wave<512, 512, 9, 1>(yh0, y, wid, ws_acc, 0, rawI, rawJ);
    } else if (wid < 5120) {
        level_wave<256, 256, 9, 2>(yh1, y, wid - 4096, ws_acc, 1, rawI, rawJ);
    } else if (wid < 5376) {
        level_wave<128, 128, 7, 4>(yh2, y, wid - 5120, ws_acc, 2, rawI, rawJ);
    } else {
        level_wave<64, 64, 5, 8>(yh3, y, wid - 5376, ws_acc, 3, rawI, rawJ);
    }
}

__global__ void hier_finalize_kernel(const float* __restrict__ ws_acc, float* __restrict__ out)
{
    if (threadIdx.x == 0 && blockIdx.x == 0) {
        const float wts[4] = {1.0f, 0.5f, 0.25f, 0.125f};
        float total = 0.f;
#pragma unroll
        for (int lv = 0; lv < 4; ++lv) {
            float l2s = 0.f, ccs = 0.f;
            for (int s = 0; s < NSLOT; ++s) {
                l2s += ws_acc[(lv * 2 + 0) * NSLOT + s];
                ccs += ws_acc[(lv * 2 + 1) * NSLOT + s];
            }
            float l2  = l2s / 32.0f;
            float ncc = -ccs / (32.0f * 100.0f);
            float ll  = wts[lv] * (l2 + ncc) * 0.5f;
            out[1 + lv] = ll;
            total += ll;
        }
        out[0] = total;
    }
}

extern "C" void kernel_launch(void* const* d_in, const int* in_sizes, int n_in,
                              void* d_out, int out_size, void* d_ws, size_t ws_size,
                              hipStream_t stream)
{
    const float* yh0 = (const float*)d_in[0];
    const float* yh1 = (const float*)d_in[1];
    const float* yh2 = (const float*)d_in[2];
    const float* yh3 = (const float*)d_in[3];
    const float* y   = (const float*)d_in[4];
    float* ws_acc = (float*)d_ws;
    float* out = (float*)d_out;

    hipMemsetAsync(ws_acc, 0, 8 * NSLOT * sizeof(float), stream);
    hier_loss_kernel<<<5440 / (NT / 64), NT, 0, stream>>>(yh0, yh1, yh2, yh3, y, ws_acc);
    hier_finalize_kernel<<<1, 64, 0, stream>>>(ws_acc, out);
}